// Round 1
// baseline (123.696 us; speedup 1.0000x reference)
//
#include <hip/hip_runtime.h>
#include <math.h>

#define TPB 256

// Knot j of the extended uniform grid: t_j = (j-3)*h + GRID_LO, h=0.4
__device__ __forceinline__ float knotf(int j) {
  return (float)(j - 3) * 0.4f - 1.0f;
}

// f[0] = silu(x); f[1..8] = the 8 cubic B-spline basis values (Cox-de Boor,
// exactly mirroring the reference recursion on the fp32-rounded knots).
__device__ __forceinline__ void kan_feat(float x, float* __restrict__ f) {
  float e = __expf(-x);
  f[0] = x * __builtin_amdgcn_rcpf(1.0f + e);

  float dx[12];
#pragma unroll
  for (int j = 0; j < 12; ++j) dx[j] = x - knotf(j);

  float b[11];
#pragma unroll
  for (int j = 0; j < 11; ++j)
    b[j] = (x >= knotf(j) && x < knotf(j + 1)) ? 1.0f : 0.0f;

#pragma unroll
  for (int k = 1; k <= 3; ++k) {
#pragma unroll
    for (int j = 0; j < 11 - k; ++j) {
      // constants fold at compile time after unrolling
      float invA = 1.0f / (knotf(j + k) - knotf(j));
      float invB = 1.0f / (knotf(j + k + 1) - knotf(j + 1));
      b[j] = fmaf(dx[j] * invA, b[j], (-dx[j + k + 1] * invB) * b[j + 1]);
    }
  }
#pragma unroll
  for (int g = 0; g < 8; ++g) f[1 + g] = b[g];
}

// One workgroup per batch element. Whole pipeline (conv1+pool1+conv2+pool2)
// fused through LDS. Weights are read from global with wave-uniform,
// compile-time offsets -> scalar loads (SGPR), leaving VALU/LDS pipes for
// the feature math.
__global__ __launch_bounds__(TPB) void kan_fwd(
    const float* __restrict__ x,
    const float* __restrict__ bw1, const float* __restrict__ sw1,
    const float* __restrict__ sc1,
    const float* __restrict__ bw2, const float* __restrict__ sw2,
    const float* __restrict__ sc2,
    float* __restrict__ out)
{
  __shared__ float F1[30 * 30 * 9];      // layer-1 input features, padded (32.4 KB)
  __shared__ float F2[2 * 16 * 16 * 9];  // layer-2 input features, padded (18.4 KB)
  __shared__ float P[2 * 49 * 8];        // layer-2 per-ci partials (3.1 KB)

  const int tid = threadIdx.x;
  const int b = blockIdx.x;
  const float* xb = x + b * 784;

  // Features of the zero-padding value (basis(0) != 0 -- must not be zeros!)
  float F0[9];
  kan_feat(0.0f, F0);

  // ---- Stage 1: per-pixel features of x into padded F1; F2 border init ----
  for (int i = tid; i < 900; i += TPB) {
    int r = i / 30, c = i % 30;
    float f[9];
    if (r >= 1 && r <= 28 && c >= 1 && c <= 28) {
      kan_feat(xb[(r - 1) * 28 + (c - 1)], f);
    } else {
#pragma unroll
      for (int k = 0; k < 9; ++k) f[k] = F0[k];
    }
#pragma unroll
    for (int k = 0; k < 9; ++k) F1[i * 9 + k] = f[k];
  }
  for (int i = tid; i < 512; i += TPB) {
    int rr = (i % 256) / 16, cc = i % 16;
    if (rr == 0 || rr == 15 || cc == 0 || cc == 15) {
#pragma unroll
      for (int k = 0; k < 9; ++k) F2[i * 9 + k] = F0[k];
    }
  }
  __syncthreads();

  // ---- Stage 2: layer-1 conv (both out ch) + 2x2 maxpool + layer-2 feats ----
  // One thread per pooled position (14x14=196). The 4 conv outputs of the
  // pool quad share a 4x4 pixel window: load each pixel's 9 features once.
  if (tid < 196) {
    int ph = tid / 14, pw = tid % 14;
    float a[2][2][2];
#pragma unroll
    for (int o = 0; o < 2; ++o)
#pragma unroll
      for (int dh = 0; dh < 2; ++dh)
#pragma unroll
        for (int dw = 0; dw < 2; ++dw) a[o][dh][dw] = 0.0f;

#pragma unroll
    for (int r = 0; r < 4; ++r) {
#pragma unroll
      for (int c = 0; c < 4; ++c) {
        const float* Fp = &F1[((2 * ph + r) * 30 + (2 * pw + c)) * 9];
        float fv[9];
#pragma unroll
        for (int k = 0; k < 9; ++k) fv[k] = Fp[k];
#pragma unroll
        for (int dh = 0; dh < 2; ++dh) {
          if (r - dh < 0 || r - dh > 2) continue;
#pragma unroll
          for (int dw = 0; dw < 2; ++dw) {
            if (c - dw < 0 || c - dw > 2) continue;
            const int tap = (r - dh) * 3 + (c - dw);
#pragma unroll
            for (int o = 0; o < 2; ++o) {
              float t = 0.0f;
#pragma unroll
              for (int g = 0; g < 8; ++g)
                t = fmaf(fv[1 + g], sw1[(o * 9 + tap) * 8 + g], t);
              float acc = a[o][dh][dw];
              acc = fmaf(t, sc1[o * 9 + tap], acc);   // standalone spline scaler
              acc = fmaf(fv[0], bw1[o * 9 + tap], acc); // silu * base_w
              a[o][dh][dw] = acc;
            }
          }
        }
      }
    }
#pragma unroll
    for (int o = 0; o < 2; ++o) {
      float m = fmaxf(fmaxf(a[o][0][0], a[o][0][1]),
                      fmaxf(a[o][1][0], a[o][1][1]));
      float f[9];
      kan_feat(m, f);
      float* Fq = &F2[((o * 16 + (ph + 1)) * 16 + (pw + 1)) * 9];
#pragma unroll
      for (int k = 0; k < 9; ++k) Fq[k] = f[k];
    }
  }
  __syncthreads();

  // ---- Stage 3: layer-2 conv partials, one wave per input channel ----
  if (tid < 128) {
    const int ci = __builtin_amdgcn_readfirstlane(tid >> 6); // wave-uniform
    const int lane = tid & 63;
    if (lane < 49) {
      int ph = lane / 7, pw = lane % 7;
      float pa[8];
#pragma unroll
      for (int q = 0; q < 8; ++q) pa[q] = 0.0f;
#pragma unroll
      for (int r = 0; r < 4; ++r) {
#pragma unroll
        for (int c = 0; c < 4; ++c) {
          const float* Fp = &F2[((ci * 16 + 2 * ph + r) * 16 + (2 * pw + c)) * 9];
          float fv[9];
#pragma unroll
          for (int k = 0; k < 9; ++k) fv[k] = Fp[k];
#pragma unroll
          for (int dh = 0; dh < 2; ++dh) {
            if (r - dh < 0 || r - dh > 2) continue;
#pragma unroll
            for (int dw = 0; dw < 2; ++dw) {
              if (c - dw < 0 || c - dw > 2) continue;
              const int tap = (r - dh) * 3 + (c - dw);
#pragma unroll
              for (int o = 0; o < 2; ++o) {
                const int wi = (o * 2 + ci) * 9 + tap;
                float t = 0.0f;
#pragma unroll
                for (int g = 0; g < 8; ++g)
                  t = fmaf(fv[1 + g], sw2[wi * 8 + g], t);
                float acc = pa[o * 4 + dh * 2 + dw];
                acc = fmaf(t, sc2[wi], acc);
                acc = fmaf(fv[0], bw2[wi], acc);
                pa[o * 4 + dh * 2 + dw] = acc;
              }
            }
          }
        }
      }
#pragma unroll
      for (int q = 0; q < 8; ++q)
        P[(ci * 49 + (ph * 7 + pw)) * 8 + q] = pa[q];
    }
  }
  __syncthreads();

  // ---- Stage 4: sum input channels, 2x2 maxpool, write output ----
  if (tid < 98) {
    int o = tid / 49, pos = tid % 49;
    float m = -INFINITY;
#pragma unroll
    for (int q = 0; q < 4; ++q) {
      float v = P[pos * 8 + o * 4 + q] + P[(49 + pos) * 8 + o * 4 + q];
      m = fmaxf(m, v);
    }
    out[b * 98 + tid] = m;  // tid = o*49 + ph*7 + pw  == flatten of (2,7,7)
  }
}

extern "C" void kernel_launch(void* const* d_in, const int* in_sizes, int n_in,
                              void* d_out, int out_size, void* d_ws, size_t ws_size,
                              hipStream_t stream) {
  const float* x   = (const float*)d_in[0];
  const float* bw1 = (const float*)d_in[1];
  const float* sw1 = (const float*)d_in[2];
  const float* sc1 = (const float*)d_in[3];
  const float* bw2 = (const float*)d_in[4];
  const float* sw2 = (const float*)d_in[5];
  const float* sc2 = (const float*)d_in[6];
  float* out = (float*)d_out;
  const int B = in_sizes[0] / 784;  // 2048
  kan_fwd<<<B, TPB, 0, stream>>>(x, bw1, sw1, sc1, bw2, sw2, sc2, out);
}

// Round 2
// 85.515 us; speedup vs baseline: 1.4465x; 1.4465x over previous
//
#include <hip/hip_runtime.h>
#include <math.h>

typedef _Float16 half_t;
typedef _Float16 h2 __attribute__((ext_vector_type(2)));
typedef unsigned int uint;

#define TPB 256

// pack two floats into a half2 bit pattern
__device__ __forceinline__ uint pack_h2f(float a, float b) {
  half_t ha = (half_t)a, hb = (half_t)b;
  unsigned short ua = __builtin_bit_cast(unsigned short, ha);
  unsigned short ub = __builtin_bit_cast(unsigned short, hb);
  return (uint)ua | ((uint)ub << 16);
}

// acc += silu*bw + sum_g basis[g]*w[g]   (fp16 dot2 pairs, fp32 accumulate)
// w points at 5 uniform dwords: 4x half2 spline weights (*scaler), 1x f32 base_w
__device__ __forceinline__ float dot8(uint d0, uint d1, uint d2, uint d3,
                                      float sv, const uint* __restrict__ w,
                                      float acc) {
  acc = fmaf(sv, __uint_as_float(w[4]), acc);
#if __has_builtin(__builtin_amdgcn_fdot2)
  acc = __builtin_amdgcn_fdot2(__builtin_bit_cast(h2, d0), __builtin_bit_cast(h2, w[0]), acc, false);
  acc = __builtin_amdgcn_fdot2(__builtin_bit_cast(h2, d1), __builtin_bit_cast(h2, w[1]), acc, false);
  acc = __builtin_amdgcn_fdot2(__builtin_bit_cast(h2, d2), __builtin_bit_cast(h2, w[2]), acc, false);
  acc = __builtin_amdgcn_fdot2(__builtin_bit_cast(h2, d3), __builtin_bit_cast(h2, w[3]), acc, false);
#else
  uint dd[4] = {d0, d1, d2, d3};
#pragma unroll
  for (int k = 0; k < 4; ++k) {
    h2 f = __builtin_bit_cast(h2, dd[k]);
    h2 wv = __builtin_bit_cast(h2, w[k]);
    acc = fmaf((float)f.x, (float)wv.x, acc);
    acc = fmaf((float)f.y, (float)wv.y, acc);
  }
#endif
  return acc;
}

// Uniform-knot cubic B-spline features of x, stored to a 6-dword LDS slot:
// halves 0..7 = dense 8-basis (fp16), dword4 = silu (fp32), dword5 = trash pad.
// Only 4 basis values are nonzero (cardinal spline); scatter them, rest zeros.
// Out-of-range scatter targets are redirected to the pad dword (half 10).
__device__ __forceinline__ void feat_store(float x, uint* __restrict__ slot) {
  float e = __expf(-x);
  float silu = x * __builtin_amdgcn_rcpf(1.0f + e);
  float s = fmaf(x, 2.5f, 5.5f);       // (x+2.2)/0.4
  float sf = floorf(s);
  float t = s - sf;
  int i = (int)sf;                     // knot interval; basis g = i-3..i nonzero
  float omt = 1.0f - t;
  float t2 = t * t;
  float B[4];
  B[0] = (1.0f / 6.0f) * omt * omt * omt;          // N3(3+t)
  B[3] = (1.0f / 6.0f) * t2 * t;                   // N3(t)
  B[1] = fmaf(0.5f * t, t2, 2.0f / 3.0f - t2);     // N3(2+t)
  B[2] = 1.0f - B[0] - B[1] - B[3];                // partition of unity
  *(uint2*)(slot) = make_uint2(0u, 0u);
  *(uint2*)(slot + 2) = make_uint2(0u, 0u);
  slot[4] = __float_as_uint(silu);
  half_t* hp = (half_t*)slot;
  const int p = i - 3;
#pragma unroll
  for (int k = 0; k < 4; ++k) {
    int g = p + k;
    int tgt = ((uint)g < 8u) ? g : 10;  // out-of-window -> pad
    hp[tgt] = (half_t)B[k];
  }
}

// Precompute packed fp16 weights into d_ws:
// W[t*5]        t=o*9+tap        (layer 1, 18 entries)
// W[90 + q*5]   q=(o*2+ci)*9+tap (layer 2, 36 entries)
__global__ void pack_w(const float* __restrict__ bw1, const float* __restrict__ sw1,
                       const float* __restrict__ sc1, const float* __restrict__ bw2,
                       const float* __restrict__ sw2, const float* __restrict__ sc2,
                       uint* __restrict__ W) {
  const int t = threadIdx.x;
  if (t < 18) {
    const float scv = sc1[t];
    uint* dst = W + t * 5;
#pragma unroll
    for (int j = 0; j < 4; ++j)
      dst[j] = pack_h2f(sw1[t * 8 + 2 * j] * scv, sw1[t * 8 + 2 * j + 1] * scv);
    dst[4] = __float_as_uint(bw1[t]);
  } else if (t < 54) {
    const int q = t - 18;
    const float scv = sc2[q];
    uint* dst = W + 90 + q * 5;
#pragma unroll
    for (int j = 0; j < 4; ++j)
      dst[j] = pack_h2f(sw2[q * 8 + 2 * j] * scv, sw2[q * 8 + 2 * j + 1] * scv);
    dst[4] = __float_as_uint(bw2[q]);
  }
}

__global__ __launch_bounds__(TPB, 5) void kan_fwd(
    const float* __restrict__ x, const uint* __restrict__ W,
    float* __restrict__ out)
{
  // 6 dwords (24 B) per pixel slot
  __shared__ __align__(16) uint lds[5400 + 2352];  // 31 KB -> 5 blocks/CU
  uint* F1 = lds;            // 900 slots (30x30 padded)
  uint* F2 = lds + 5400;     // 2 x 196 slots (14x14, unpadded)
  float* P = (float*)lds;    // stage>=3: 4*49*4 partials (F1 region is dead)

  const int tid = threadIdx.x;
  const float* xb = x + (size_t)blockIdx.x * 784;

  // ---- Stage 1: features of padded 30x30 input ----
  for (int ii = tid; ii < 900; ii += TPB) {
    int r = ii / 30, c = ii % 30;
    bool inter = ((uint)(r - 1) < 28u) && ((uint)(c - 1) < 28u);
    int xi = (r - 1) * 28 + (c - 1);
    xi = min(max(xi, 0), 783);
    float xv = xb[xi];
    xv = inter ? xv : 0.0f;              // padding pixels get features of 0
    feat_store(xv, F1 + ii * 6);
  }
  __syncthreads();

  // ---- Stage 2: layer-1 conv (2x2 pool quad per thread) + pool + features ----
  if (tid < 196) {
    const int ph = tid / 14, pw = tid % 14;
    float acc[2][4];
#pragma unroll
    for (int o = 0; o < 2; ++o)
#pragma unroll
      for (int q = 0; q < 4; ++q) acc[o][q] = 0.0f;
#pragma unroll
    for (int r = 0; r < 4; ++r) {
#pragma unroll
      for (int c = 0; c < 4; ++c) {
        const uint* sl = F1 + ((2 * ph + r) * 30 + (2 * pw + c)) * 6;
        uint2 a = *(const uint2*)sl;
        uint2 bq = *(const uint2*)(sl + 2);
        float sv = __uint_as_float(sl[4]);
#pragma unroll
        for (int dh = 0; dh < 2; ++dh) {
          if (r - dh < 0 || r - dh > 2) continue;
#pragma unroll
          for (int dw = 0; dw < 2; ++dw) {
            if (c - dw < 0 || c - dw > 2) continue;
            const int tap = (r - dh) * 3 + (c - dw);
#pragma unroll
            for (int o = 0; o < 2; ++o)
              acc[o][dh * 2 + dw] =
                  dot8(a.x, a.y, bq.x, bq.y, sv, W + (o * 9 + tap) * 5, acc[o][dh * 2 + dw]);
          }
        }
      }
    }
#pragma unroll
    for (int o = 0; o < 2; ++o) {
      float m = fmaxf(fmaxf(acc[o][0], acc[o][1]), fmaxf(acc[o][2], acc[o][3]));
      feat_store(m, F2 + (o * 196 + tid) * 6);
    }
  }
  __syncthreads();

  // ---- Stage 3: layer-2 conv; one wave per (o,ci), lane = 7x7 pool pos ----
  {
    const int wid = __builtin_amdgcn_readfirstlane(tid >> 6);  // = o*2+ci
    const int lane = tid & 63;
    // features of x=0 (padding): i=5, t=0.5 -> basis g=2..5
    const uint F0d1 = pack_h2f(1.0f / 48.0f, 23.0f / 48.0f);
    const uint F0d2 = pack_h2f(23.0f / 48.0f, 1.0f / 48.0f);
    if (lane < 49) {
      const int ci = wid & 1;
      const int ph = lane / 7, pw = lane % 7;
      float pa[4] = {0.0f, 0.0f, 0.0f, 0.0f};
#pragma unroll
      for (int r = 0; r < 4; ++r) {
#pragma unroll
        for (int c = 0; c < 4; ++c) {
          int row = 2 * ph + r - 1, col = 2 * pw + c - 1;
          bool ok = ((uint)row < 14u) && ((uint)col < 14u);
          int rcl = min(max(row, 0), 13), ccl = min(max(col, 0), 13);
          const uint* sl = F2 + (ci * 196 + rcl * 14 + ccl) * 6;
          uint2 a = *(const uint2*)sl;
          uint2 bq = *(const uint2*)(sl + 2);
          float sv = ok ? __uint_as_float(sl[4]) : 0.0f;
          uint d0 = ok ? a.x : 0u;
          uint d1 = ok ? a.y : F0d1;
          uint d2 = ok ? bq.x : F0d2;
          uint d3 = ok ? bq.y : 0u;
#pragma unroll
          for (int dh = 0; dh < 2; ++dh) {
            if (r - dh < 0 || r - dh > 2) continue;
#pragma unroll
            for (int dw = 0; dw < 2; ++dw) {
              if (c - dw < 0 || c - dw > 2) continue;
              const int tap = (r - dh) * 3 + (c - dw);
              pa[dh * 2 + dw] =
                  dot8(d0, d1, d2, d3, sv, W + 90 + (wid * 9 + tap) * 5, pa[dh * 2 + dw]);
            }
          }
        }
      }
      *(float4*)&P[(wid * 49 + lane) * 4] = make_float4(pa[0], pa[1], pa[2], pa[3]);
    }
  }
  __syncthreads();

  // ---- Stage 4: sum over ci, 2x2 maxpool, write (2,7,7) flat ----
  if (tid < 98) {
    const int o = tid / 49, pos = tid % 49;
    const float4 p0 = *(const float4*)&P[((o * 2 + 0) * 49 + pos) * 4];
    const float4 p1 = *(const float4*)&P[((o * 2 + 1) * 49 + pos) * 4];
    float m = fmaxf(fmaxf(p0.x + p1.x, p0.y + p1.y), fmaxf(p0.z + p1.z, p0.w + p1.w));
    out[(size_t)blockIdx.x * 98 + tid] = m;
  }
}

extern "C" void kernel_launch(void* const* d_in, const int* in_sizes, int n_in,
                              void* d_out, int out_size, void* d_ws, size_t ws_size,
                              hipStream_t stream) {
  const float* x   = (const float*)d_in[0];
  const float* bw1 = (const float*)d_in[1];
  const float* sw1 = (const float*)d_in[2];
  const float* sc1 = (const float*)d_in[3];
  const float* bw2 = (const float*)d_in[4];
  const float* sw2 = (const float*)d_in[5];
  const float* sc2 = (const float*)d_in[6];
  float* out = (float*)d_out;
  uint* W = (uint*)d_ws;  // 270 dwords
  const int B = in_sizes[0] / 784;  // 2048
  pack_w<<<1, 64, 0, stream>>>(bw1, sw1, sc1, bw2, sw2, sc2, W);
  kan_fwd<<<B, TPB, 0, stream>>>(x, W, out);
}